// Round 6
// baseline (101.238 us; speedup 1.0000x reference)
//
#include <hip/hip_runtime.h>
#include <math.h>

// Problem constants (fixed shapes from reference)
#define KNUM 256
#define HH 62
#define WW 64
#define BB 768            // N*C = 4*192
#define JV 1024           // vectors per plane = W*Hp/D = 64*64/4
#define M_TOT (BB*JV)     // 786432
#define QL_SIZE (BB*HH*WW) // 3047424

// d_out layout (concatenated tuple, float32):
#define OFF_MSE   QL_SIZE
#define OFF_INDS  (QL_SIZE + 1)
#define OFF_RATE  (OFF_INDS + M_TOT)

// d_ws layout (floats): per-block partials
#define WS_MSE  0
#define WS_RATE 768

#define XT_STRIDE 65   // bank(w*65+h) = (w+h)%32 -> all phases <=2-way (conflict-free)
#define TAB_STRIDE 12  // 48B per pair-entry: every entry 16B-aligned (b128+b128+b64)

typedef float v2f __attribute__((ext_vector_type(2)));

// v_pk_fma_f32 d = c*y + acc, with src1 (y) broadcast from ONE 32-bit half to
// both output halves via op_sel/op_sel_hi (verified correct R5, absmax 0.0).
__device__ __forceinline__ v2f pk_fma_ylo(v2f c, v2f y, v2f acc) {
    v2f d;
    asm("v_pk_fma_f32 %0, %1, %2, %3 op_sel:[0,0,0] op_sel_hi:[1,0,1]"
        : "=v"(d) : "v"(c), "v"(y), "v"(acc));
    return d;
}
__device__ __forceinline__ v2f pk_fma_ylo_acc(v2f c, v2f y, v2f d) {
    asm("v_pk_fma_f32 %0, %1, %2, %0 op_sel:[0,0,0] op_sel_hi:[1,0,1]"
        : "+v"(d) : "v"(c), "v"(y));
    return d;
}
__device__ __forceinline__ v2f pk_fma_yhi_acc(v2f c, v2f y, v2f d) {
    asm("v_pk_fma_f32 %0, %1, %2, %0 op_sel:[0,1,0] op_sel_hi:[1,1,1]"
        : "+v"(d) : "v"(c), "v"(y));
    return d;
}

// 768 blocks x 256 threads. Codeword range split across wave-halves (waves
// 0-1: k<128, waves 2-3: k>=128) -> halves per-CU LDS broadcast traffic.
// 8 vectors/thread. Explicit prefetch-by-1 on the codebook table breaks the
// ds_read->wait->compute convoy. (256,3): 3 blocks/CU, VGPR cap ~168.
__launch_bounds__(256, 3)
__global__ void vq_main(const float* __restrict__ latents,
                        const float* __restrict__ codebook,
                        const float* __restrict__ log_pmf,
                        float* __restrict__ ws_out,
                        float* __restrict__ out) {
    __shared__ __align__(16) float xt[64 * XT_STRIDE];     // transposed plane [w][h]
    __shared__ __align__(16) float tab[129 * TAB_STRIDE];  // pair-interleaved codebook (+1 pad)
    __shared__ float4 cbv[KNUM];                           // epilogue gather
    __shared__ float  l2v[KNUM];
    __shared__ float  ex_d[JV];                            // cross-half argmin exchange
    __shared__ int    ex_k[JV];
    __shared__ float  wred[8];

    const int t  = threadIdx.x;
    const int tl = t & 127;         // thread within wave-half
    const int half = t >> 7;        // 0: waves 0-1 (k<128), 1: waves 2-3 (k>=128)
    const int b = blockIdx.x;
    const float* lat = latents + (size_t)b * (HH * WW);

    // ---- stage pair-interleaved codebook table (first 128 threads) ----
    if (t < 128) {
        float4 c0 = ((const float4*)codebook)[2 * t];
        float4 c1 = ((const float4*)codebook)[2 * t + 1];
        float l20 = log_pmf[2 * t]     * (-1.44269504088896340736f);
        float l21 = log_pmf[2 * t + 1] * (-1.44269504088896340736f);
        float q0 = c0.x * c0.x + c0.y * c0.y + c0.z * c0.z + c0.w * c0.w + l20 * 100.0f;
        float q1 = c1.x * c1.x + c1.y * c1.y + c1.z * c1.z + c1.w * c1.w + l21 * 100.0f;
        float* e = &tab[t * TAB_STRIDE];
        e[0] = c0.x; e[1] = c1.x; e[2] = c0.y; e[3] = c1.y;
        e[4] = c0.z; e[5] = c1.z; e[6] = c0.w; e[7] = c1.w;
        e[8] = q0;   e[9] = q1;
        cbv[2 * t] = c0; cbv[2 * t + 1] = c1;
        l2v[2 * t] = l20; l2v[2 * t + 1] = l21;
    }

    // ---- stage latents plane transposed into LDS (pad rows 62,63 = rows 60,61) ----
    for (int idx = t; idx < (HH * WW / 4); idx += 256) {
        int h  = idx >> 4;     // row 0..61
        int wq = idx & 15;     // float4 column
        float4 v = ((const float4*)lat)[idx];
        int w0 = wq * 4;
        xt[(w0 + 0) * XT_STRIDE + h] = v.x;
        xt[(w0 + 1) * XT_STRIDE + h] = v.y;
        xt[(w0 + 2) * XT_STRIDE + h] = v.z;
        xt[(w0 + 3) * XT_STRIDE + h] = v.w;
        if (h >= 60) {     // replicate rows 60,61 -> 62,63
            int h2 = h + 2;
            xt[(w0 + 0) * XT_STRIDE + h2] = v.x;
            xt[(w0 + 1) * XT_STRIDE + h2] = v.y;
            xt[(w0 + 2) * XT_STRIDE + h2] = v.z;
            xt[(w0 + 3) * XT_STRIDE + h2] = v.w;
        }
    }
    __syncthreads();

    // ---- per-thread: 8 vectors j = tl + 128*i; y = -2x as natural pairs ----
    v2f y01[8], y23[8];    // {yx,yy}, {yz,yw}
    float dmin[8];
    int   kmin[8];
#pragma unroll
    for (int i = 0; i < 8; ++i) {
        int j  = tl + 128 * i;
        int w  = j >> 4;
        int hc = j & 15;
        const float* p = &xt[w * XT_STRIDE + hc * 4];
        y01[i] = (v2f){-2.0f * p[0], -2.0f * p[1]};
        y23[i] = (v2f){-2.0f * p[2], -2.0f * p[3]};
        dmin[i] = INFINITY;
        kmin[i] = 0;
    }

    // ---- argmin over this half's 128 codewords (64 pair-bodies), prefetch-by-1 ----
    const float* eb = &tab[half * 64 * TAB_STRIDE];
    float4 f0 = *(const float4*)(eb + 0);   // {cx0,cx1,cy0,cy1}
    float4 f1 = *(const float4*)(eb + 4);   // {cz0,cz1,cw0,cw1}
    v2f    qq = *(const v2f*)(eb + 8);      // {q0,q1}
#pragma unroll 2
    for (int k2 = 0; k2 < 64; ++k2) {
        // prefetch next body (entry 128 is a pad: loaded, never consumed)
        const float* en = eb + (k2 + 1) * TAB_STRIDE;
        float4 nf0 = *(const float4*)(en + 0);
        float4 nf1 = *(const float4*)(en + 4);
        v2f    nqq = *(const v2f*)(en + 8);

        v2f cx2 = (v2f){f0.x, f0.y};
        v2f cy2 = (v2f){f0.z, f0.w};
        v2f cz2 = (v2f){f1.x, f1.y};
        v2f cw2 = (v2f){f1.z, f1.w};
        int k = half * 128 + k2 * 2;
#pragma unroll
        for (int i = 0; i < 8; ++i) {
            v2f d2 = pk_fma_ylo(cx2, y01[i], qq);        // + yx*{cx0,cx1}
            d2 = pk_fma_yhi_acc(cy2, y01[i], d2);        // + yy*{cy0,cy1}
            d2 = pk_fma_ylo_acc(cz2, y23[i], d2);        // + yz*{cz0,cz1}
            d2 = pk_fma_yhi_acc(cw2, y23[i], d2);        // + yw*{cw0,cw1}
            float nm = fminf(fminf(d2.x, d2.y), dmin[i]);   // v_min3_f32
            int kp = k + (int)(d2.y < d2.x);                // cmp + addc; tie -> lower k
            kmin[i] = (dmin[i] == nm) ? kmin[i] : kp;       // old wins ties
            dmin[i] = nm;
        }
        f0 = nf0; f1 = nf1; qq = nqq;
    }

    // ---- merge halves: high half posts (d,k); low half folds in (strict <) ----
    if (half) {
#pragma unroll
        for (int i = 0; i < 8; ++i) {
            ex_d[tl + 128 * i] = dmin[i];
            ex_k[tl + 128 * i] = kmin[i];
        }
    }
    __syncthreads();

    float mse_acc = 0.0f;
    float rate_acc = 0.0f;
    if (!half) {
#pragma unroll
        for (int i = 0; i < 8; ++i) {
            int j = tl + 128 * i;
            float dh = ex_d[j];
            int   kh = ex_k[j];
            // strict <: ties go to low half = smaller k = first occurrence
            bool hi = dh < dmin[i];
            kmin[i] = hi ? kh : kmin[i];

            int w  = j >> 4;
            int hc = j & 15;
            float4 c = cbv[kmin[i]];
            rate_acc += l2v[kmin[i]];
            float e0 = fmaf(0.5f, y01[i].x, c.x);   // c - x
            float e1 = fmaf(0.5f, y01[i].y, c.y);
            float e2 = fmaf(0.5f, y23[i].x, c.z);
            float e3 = fmaf(0.5f, y23[i].y, c.w);
            mse_acc += e0 * e0 + e1 * e1 + e2 * e2 + e3 * e3;
            float* p = &xt[w * XT_STRIDE + hc * 4];
            p[0] = c.x; p[1] = c.y; p[2] = c.z; p[3] = c.w;   // overwrite x with q
            out[OFF_INDS + (size_t)b * JV + j] = (float)kmin[i];
        }
    }
    __syncthreads();

    // ---- coalesced crop/transpose write-out: ql[b, h, w] = xt[w][h], h < 62 ----
    for (int idx = t; idx < HH * WW; idx += 256) {
        int h = idx >> 6;
        int w = idx & 63;
        out[(size_t)b * (HH * WW) + idx] = xt[w * XT_STRIDE + h];
    }

    // ---- block reduction of mse/rate -> per-block partial (plain store) ----
#pragma unroll
    for (int off = 32; off > 0; off >>= 1) {
        mse_acc  += __shfl_down(mse_acc, off, 64);
        rate_acc += __shfl_down(rate_acc, off, 64);
    }
    int wave = t >> 6, lane = t & 63;
    if (lane == 0) { wred[wave] = mse_acc; wred[4 + wave] = rate_acc; }
    __syncthreads();
    if (t == 0) {
        ws_out[WS_MSE + b]  = wred[0] + wred[1] + wred[2] + wred[3];
        ws_out[WS_RATE + b] = wred[4] + wred[5] + wred[6] + wred[7];
    }
}

__global__ void vq_reduce(const float* __restrict__ ws, float* __restrict__ out) {
    __shared__ float wred[8];
    int t = threadIdx.x;   // 256 threads
    float m = ws[WS_MSE + t]  + ws[WS_MSE + 256 + t]  + ws[WS_MSE + 512 + t];
    float r = ws[WS_RATE + t] + ws[WS_RATE + 256 + t] + ws[WS_RATE + 512 + t];
#pragma unroll
    for (int off = 32; off > 0; off >>= 1) {
        m += __shfl_down(m, off, 64);
        r += __shfl_down(r, off, 64);
    }
    int wave = t >> 6, lane = t & 63;
    if (lane == 0) { wred[wave] = m; wred[4 + wave] = r; }
    __syncthreads();
    if (t == 0) {
        out[OFF_MSE]      = (wred[0] + wred[1] + wred[2] + wred[3]) * (1.0f / 3145728.0f);
        out[OFF_RATE]     = wred[4] + wred[5] + wred[6] + wred[7];
        out[OFF_RATE + 1] = 0.0f;
        out[OFF_RATE + 2] = 0.0f;
    }
}

extern "C" void kernel_launch(void* const* d_in, const int* in_sizes, int n_in,
                              void* d_out, int out_size, void* d_ws, size_t ws_size,
                              hipStream_t stream) {
    const float* latents  = (const float*)d_in[0];
    const float* codebook = (const float*)d_in[1];
    const float* log_pmf  = (const float*)d_in[2];
    float* out = (float*)d_out;
    float* ws  = (float*)d_ws;

    vq_main<<<BB, 256, 0, stream>>>(latents, codebook, log_pmf, ws, out);
    vq_reduce<<<1, 256, 0, stream>>>(ws, out);
}